// Round 1
// baseline (84.760 us; speedup 1.0000x reference)
//
#include <hip/hip_runtime.h>
#include <math.h>

constexpr int NW = 14;
constexpr int DIM = 1 << NW;      // 16384
constexpr int BATCH = 256;
constexpr int NT = 512;           // 8 waves

__global__ __launch_bounds__(NT, 1) void qsim(const float* __restrict__ state,
                                              const float* __restrict__ params,
                                              const float* __restrict__ head_w,
                                              const float* __restrict__ head_b,
                                              float* __restrict__ out)
{
    __shared__ float re[DIM];           // 64 KiB
    __shared__ float im[DIM];           // 64 KiB
    __shared__ float cosv[NW * 3 * 2];  // 84 gate half-angle cosines
    __shared__ float sinv[NW * 3 * 2];
    __shared__ float partial[NT / 64];

    const int b = blockIdx.x;
    const int tid = threadIdx.x;

    // Precompute sincos of all 84 params (half angles) once per block.
    if (tid < NW * 3 * 2) {
        float sv, cv;
        sincosf(params[tid] * 0.5f, &sv, &cv);
        sinv[tid] = sv;
        cosv[tid] = cv;
    }

    // Load state (imag = 0). Coalesced.
    const float* __restrict__ sp = state + (size_t)b * DIM;
    #pragma unroll
    for (int j = 0; j < DIM / NT; ++j) {
        int i = tid + j * NT;
        re[i] = sp[i];
        im[i] = 0.0f;
    }
    __syncthreads();

    // 2 layers x 14 wires; each pass applies RY,RZ (wire w) + CNOT(w,w+1) + RX (wire w)
    // as one fused op on the 4 amplitudes spanned by bits (pw, pt).
    for (int g = 0; g < 2 * NW; ++g) {
        const int w = (g >= NW) ? (g - NW) : g;
        const int base3 = g * 3;
        const float cy = cosv[base3 + 0], sy = sinv[base3 + 0];
        const float c1 = cosv[base3 + 1], s1 = sinv[base3 + 1];
        const float cx = cosv[base3 + 2], sx = sinv[base3 + 2];

        const int pw = NW - 1 - w;                    // bit of wire w
        const int pt = NW - 1 - ((w + 1) % NW);       // bit of target wire
        const int hi = pw > pt ? pw : pt;
        const int lo = pw > pt ? pt : pw;
        const unsigned bw = 1u << pw;
        const unsigned bt = 1u << pt;
        const unsigned mlo = (1u << lo) - 1u;
        const unsigned mmid = (1u << (hi - 1 - lo)) - 1u;
        const int shmid = hi - 1 - lo;

        #pragma unroll
        for (int j = 0; j < DIM / 4 / NT; ++j) {
            const unsigned q = (unsigned)(tid + j * NT);
            const unsigned low  = q & mlo;
            const unsigned rest = q >> lo;
            const unsigned mid  = rest & mmid;
            const unsigned high = rest >> shmid;
            const unsigned i00 = (high << (hi + 1)) | (mid << (lo + 1)) | low;
            const unsigned iw  = i00 | bw;        // w=1, t=0
            const unsigned it  = i00 | bt;        // w=0, t=1
            const unsigned i11 = i00 | bw | bt;   // w=1, t=1

            float a00r = re[i00], a00i = im[i00];
            float a10r = re[iw],  a10i = im[iw];
            float a01r = re[it],  a01i = im[it];
            float a11r = re[i11], a11i = im[i11];

            // RY (real) on bit w: pairs (a00,a10), (a01,a11)
            float v0r = cy * a00r - sy * a10r, v0i = cy * a00i - sy * a10i;
            float v1r = sy * a00r + cy * a10r, v1i = sy * a00i + cy * a10i;
            float u0r = cy * a01r - sy * a11r, u0i = cy * a01i - sy * a11i;
            float u1r = sy * a01r + cy * a11r, u1i = sy * a01i + cy * a11i;

            // RZ phase: w=0 rows *= (c1 - i s1); w=1 rows *= (c1 + i s1)
            float b00r = c1 * v0r + s1 * v0i, b00i = c1 * v0i - s1 * v0r;
            float b10r = c1 * v1r - s1 * v1i, b10i = c1 * v1i + s1 * v1r;
            float b01r = c1 * u0r + s1 * u0i, b01i = c1 * u0i - s1 * u0r;
            float b11r = c1 * u1r - s1 * u1i, b11i = c1 * u1i + s1 * u1r;

            // CNOT(w->t) then RX on w:
            // o00 = cx*b00 - i sx*b11 ; o10 = -i sx*b00 + cx*b11
            // o01 = cx*b01 - i sx*b10 ; o11 = -i sx*b01 + cx*b10
            float o00r = cx * b00r + sx * b11i, o00i = cx * b00i - sx * b11r;
            float o10r = sx * b00i + cx * b11r, o10i = cx * b11i - sx * b00r;
            float o01r = cx * b01r + sx * b10i, o01i = cx * b01i - sx * b10r;
            float o11r = sx * b01i + cx * b10r, o11i = cx * b10i - sx * b01r;

            re[i00] = o00r; im[i00] = o00i;
            re[iw]  = o10r; im[iw]  = o10i;
            re[it]  = o01r; im[it]  = o01i;
            re[i11] = o11r; im[i11] = o11i;
        }
        __syncthreads();
    }

    // Epilogue: out[b] = sum_i |amp_i|^2 * g(i) + head_b
    // g(i) = sum_w hw[w] * (1 - 2*bit(i, 13-w))
    float hw[NW];
    #pragma unroll
    for (int w = 0; w < NW; ++w) hw[w] = head_w[w];

    float acc = 0.0f;
    #pragma unroll
    for (int j = 0; j < DIM / NT; ++j) {
        int i = tid + j * NT;
        float p = re[i] * re[i] + im[i] * im[i];
        float gsum = 0.0f;
        #pragma unroll
        for (int w = 0; w < NW; ++w) {
            gsum = ((i >> (NW - 1 - w)) & 1) ? (gsum - hw[w]) : (gsum + hw[w]);
        }
        acc += p * gsum;
    }
    #pragma unroll
    for (int off = 32; off > 0; off >>= 1) acc += __shfl_down(acc, off);
    if ((tid & 63) == 0) partial[tid >> 6] = acc;
    __syncthreads();
    if (tid == 0) {
        float tot = 0.0f;
        #pragma unroll
        for (int k = 0; k < NT / 64; ++k) tot += partial[k];
        out[b] = tot + head_b[0];
    }
}

extern "C" void kernel_launch(void* const* d_in, const int* in_sizes, int n_in,
                              void* d_out, int out_size, void* d_ws, size_t ws_size,
                              hipStream_t stream) {
    const float* state  = (const float*)d_in[0];
    const float* params = (const float*)d_in[1];
    const float* head_w = (const float*)d_in[2];
    const float* head_b = (const float*)d_in[3];
    float* outp = (float*)d_out;
    qsim<<<BATCH, NT, 0, stream>>>(state, params, head_w, head_b, outp);
}

// Round 2
// 36.602 us; speedup vs baseline: 2.3157x; 2.3157x over previous
//
#include <hip/hip_runtime.h>
#include <math.h>

constexpr int NW = 14;
constexpr int DIM = 1 << NW;      // 16384
constexpr int BATCH = 256;
constexpr int NT = 512;           // 8 waves; each thread owns 32 amplitudes

// LDS bank swizzle: XOR bits 9..5 into bits 4..0. Bijective; makes every
// pass's 64-lane access pattern <=2-way (free on CDNA4).
__device__ __forceinline__ int swz(int i) { return i ^ ((i >> 5) & 31); }

// Fused RY/RZ/CNOT/RX on local bits JW (wire) and JT (target), applied to the
// 32-amplitude register block. 8 quads per gate, fully unrolled.
template<int JW, int JT>
__device__ __forceinline__ void apply_gate(float (&ar)[32], float (&ai)[32],
                                           float cy, float sy, float c1, float s1,
                                           float cx, float sx)
{
    constexpr int BW = 1 << JW, BT = 1 << JT;
    #pragma unroll
    for (int m = 0; m < 8; ++m) {
        int l00 = 0, mm = m;
        #pragma unroll
        for (int j = 0; j < 5; ++j) {
            if (j != JW && j != JT) { l00 |= (mm & 1) << j; mm >>= 1; }
        }
        const int iA = l00, iB = l00 | BW, iC = l00 | BT, iD = l00 | BW | BT;

        float a00r = ar[iA], a00i = ai[iA];
        float a10r = ar[iB], a10i = ai[iB];
        float a01r = ar[iC], a01i = ai[iC];
        float a11r = ar[iD], a11i = ai[iD];

        // RY (real) on wire bit: pairs (a00,a10), (a01,a11)
        float v0r = cy * a00r - sy * a10r, v0i = cy * a00i - sy * a10i;
        float v1r = sy * a00r + cy * a10r, v1i = sy * a00i + cy * a10i;
        float u0r = cy * a01r - sy * a11r, u0i = cy * a01i - sy * a11i;
        float u1r = sy * a01r + cy * a11r, u1i = sy * a01i + cy * a11i;

        // RZ phase: w=0 rows *= (c1 - i s1); w=1 rows *= (c1 + i s1)
        float b00r = c1 * v0r + s1 * v0i, b00i = c1 * v0i - s1 * v0r;
        float b10r = c1 * v1r - s1 * v1i, b10i = c1 * v1i + s1 * v1r;
        float b01r = c1 * u0r + s1 * u0i, b01i = c1 * u0i - s1 * u0r;
        float b11r = c1 * u1r - s1 * u1i, b11i = c1 * u1i + s1 * u1r;

        // CNOT(w->t) then RX on w:
        float o00r = cx * b00r + sx * b11i, o00i = cx * b00i - sx * b11r;
        float o10r = sx * b00i + cx * b11r, o10i = cx * b11i - sx * b00r;
        float o01r = cx * b01r + sx * b10i, o01i = cx * b01i - sx * b10r;
        float o11r = sx * b01i + cx * b10r, o11i = cx * b10i - sx * b01r;

        ar[iA] = o00r; ai[iA] = o00i;
        ar[iB] = o10r; ai[iB] = o10i;
        ar[iC] = o01r; ai[iC] = o01i;
        ar[iD] = o11r; ai[iD] = o11i;
    }
}

// Scatter thread id t (9 bits) into the 9 bit-positions NOT in {P0..P4}.
template<int P0, int P1, int P2, int P3, int P4>
__device__ __forceinline__ int base_of(int t)
{
    int base = 0, j = 0;
    #pragma unroll
    for (int p = 0; p < NW; ++p) {
        if (p != P0 && p != P1 && p != P2 && p != P3 && p != P4) {
            base |= ((t >> j) & 1) << p;
            ++j;
        }
    }
    return base;
}

template<int P0, int P1, int P2, int P3, int P4>
__device__ __forceinline__ int off_of(int l)
{
    return ((l & 1) << P0) | (((l >> 1) & 1) << P1) | (((l >> 2) & 1) << P2) |
           (((l >> 3) & 1) << P3) | (((l >> 4) & 1) << P4);
}

template<int P0, int P1, int P2, int P3, int P4>
__device__ __forceinline__ void lds_load(const float* re, const float* im,
                                         float (&ar)[32], float (&ai)[32], int base)
{
    #pragma unroll
    for (int l = 0; l < 32; ++l) {
        int s = swz(base | off_of<P0, P1, P2, P3, P4>(l));
        ar[l] = re[s];
        ai[l] = im[s];
    }
}

template<int P0, int P1, int P2, int P3, int P4>
__device__ __forceinline__ void lds_store(float* re, float* im,
                                          const float (&ar)[32], const float (&ai)[32], int base)
{
    #pragma unroll
    for (int l = 0; l < 32; ++l) {
        int s = swz(base | off_of<P0, P1, P2, P3, P4>(l));
        re[s] = ar[l];
        im[s] = ai[l];
    }
}

__global__ __launch_bounds__(NT, 1) void qsim(const float* __restrict__ state,
                                              const float* __restrict__ params,
                                              const float* __restrict__ head_w,
                                              const float* __restrict__ head_b,
                                              float* __restrict__ out)
{
    __shared__ float re[DIM];           // 64 KiB
    __shared__ float im[DIM];           // 64 KiB
    __shared__ float2 csv[NW * 3 * 2];  // (cos, sin) of half-angles, 84 gates
    __shared__ float partial[NT / 64];

    const int t = threadIdx.x;
    const int b = blockIdx.x;

    float ar[32], ai[32];

    // Pass A owns bits {9..13}: amp index = (l<<9)|t. Load from HBM directly
    // (coalesced per l across lanes); imag part of input state is zero.
    const float* __restrict__ sp = state + (size_t)b * DIM;
    #pragma unroll
    for (int l = 0; l < 32; ++l) {
        ar[l] = sp[(l << 9) | t];
        ai[l] = 0.0f;
    }

    if (t < NW * 3 * 2) {
        float sv, cv;
        sincosf(params[t] * 0.5f, &sv, &cv);
        csv[t] = make_float2(cv, sv);
    }
    __syncthreads();

#define GATE(JW, JT, G) do {                                        \
        float2 vy = csv[(G) * 3 + 0];                               \
        float2 vz = csv[(G) * 3 + 1];                               \
        float2 vx = csv[(G) * 3 + 2];                               \
        apply_gate<JW, JT>(ar, ai, vy.x, vy.y, vz.x, vz.y, vx.x, vx.y); \
    } while (0)

    // Pass A: L1 wires 0-3, bits {9,10,11,12,13}
    GATE(4, 3, 0); GATE(3, 2, 1); GATE(2, 1, 2); GATE(1, 0, 3);
    lds_store<9, 10, 11, 12, 13>(re, im, ar, ai, base_of<9, 10, 11, 12, 13>(t));
    __syncthreads();

    // Pass B: L1 wires 4-7, bits {5,6,7,8,9}
    {
        const int base = base_of<5, 6, 7, 8, 9>(t);
        lds_load<5, 6, 7, 8, 9>(re, im, ar, ai, base);
        GATE(4, 3, 4); GATE(3, 2, 5); GATE(2, 1, 6); GATE(1, 0, 7);
        lds_store<5, 6, 7, 8, 9>(re, im, ar, ai, base);
    }
    __syncthreads();

    // Pass C: L1 wires 8-11, bits {1,2,3,4,5}
    {
        const int base = base_of<1, 2, 3, 4, 5>(t);
        lds_load<1, 2, 3, 4, 5>(re, im, ar, ai, base);
        GATE(4, 3, 8); GATE(3, 2, 9); GATE(2, 1, 10); GATE(1, 0, 11);
        lds_store<1, 2, 3, 4, 5>(re, im, ar, ai, base);
    }
    __syncthreads();

    // Pass D: L1 wires 12,13 + L2 wires 0,1, bits {0,1,11,12,13}
    {
        const int base = base_of<0, 1, 11, 12, 13>(t);
        lds_load<0, 1, 11, 12, 13>(re, im, ar, ai, base);
        GATE(1, 0, 12); GATE(0, 4, 13); GATE(4, 3, 14); GATE(3, 2, 15);
        lds_store<0, 1, 11, 12, 13>(re, im, ar, ai, base);
    }
    __syncthreads();

    // Pass E: L2 wires 2-5, bits {7,8,9,10,11}
    {
        const int base = base_of<7, 8, 9, 10, 11>(t);
        lds_load<7, 8, 9, 10, 11>(re, im, ar, ai, base);
        GATE(4, 3, 16); GATE(3, 2, 17); GATE(2, 1, 18); GATE(1, 0, 19);
        lds_store<7, 8, 9, 10, 11>(re, im, ar, ai, base);
    }
    __syncthreads();

    // Pass F: L2 wires 6-9, bits {3,4,5,6,7}
    {
        const int base = base_of<3, 4, 5, 6, 7>(t);
        lds_load<3, 4, 5, 6, 7>(re, im, ar, ai, base);
        GATE(4, 3, 20); GATE(3, 2, 21); GATE(2, 1, 22); GATE(1, 0, 23);
        lds_store<3, 4, 5, 6, 7>(re, im, ar, ai, base);
    }
    __syncthreads();

    // Pass G: L2 wires 10-13, bits {0,1,2,3,13}; epilogue fused from registers.
    {
        const int base = base_of<0, 1, 2, 3, 13>(t);   // == t << 4
        lds_load<0, 1, 2, 3, 13>(re, im, ar, ai, base);
        GATE(3, 2, 24); GATE(2, 1, 25); GATE(1, 0, 26); GATE(0, 4, 27);
    }

    // Epilogue: out[b] = sum_i |amp_i|^2 * g(i) + head_b,
    // g(i) = sum_w hw[w] * (1 - 2*bit(i, 13-w)).
    // Thread bits occupy positions 4..12 (wires 9..1); local bits are
    // positions {0,1,2,3,13} -> wires {13,12,11,10,0}.
    float hw[NW];
    #pragma unroll
    for (int w = 0; w < NW; ++w) hw[w] = head_w[w];

    float gbase = 0.0f;
    #pragma unroll
    for (int j = 0; j < 9; ++j) {
        float h = hw[9 - j];
        gbase += ((t >> j) & 1) ? -h : h;
    }

    float acc = 0.0f;
    #pragma unroll
    for (int l = 0; l < 32; ++l) {
        float g = gbase;
        g += (l & 1)  ? -hw[13] : hw[13];
        g += (l & 2)  ? -hw[12] : hw[12];
        g += (l & 4)  ? -hw[11] : hw[11];
        g += (l & 8)  ? -hw[10] : hw[10];
        g += (l & 16) ? -hw[0]  : hw[0];
        float p = ar[l] * ar[l] + ai[l] * ai[l];
        acc += p * g;
    }

    #pragma unroll
    for (int off = 32; off > 0; off >>= 1) acc += __shfl_down(acc, off);
    if ((t & 63) == 0) partial[t >> 6] = acc;
    __syncthreads();
    if (t == 0) {
        float tot = 0.0f;
        #pragma unroll
        for (int k = 0; k < NT / 64; ++k) tot += partial[k];
        out[b] = tot + head_b[0];
    }
#undef GATE
}

extern "C" void kernel_launch(void* const* d_in, const int* in_sizes, int n_in,
                              void* d_out, int out_size, void* d_ws, size_t ws_size,
                              hipStream_t stream) {
    const float* state  = (const float*)d_in[0];
    const float* params = (const float*)d_in[1];
    const float* head_w = (const float*)d_in[2];
    const float* head_b = (const float*)d_in[3];
    float* outp = (float*)d_out;
    qsim<<<BATCH, NT, 0, stream>>>(state, params, head_w, head_b, outp);
}

// Round 3
// 36.308 us; speedup vs baseline: 2.3344x; 1.0081x over previous
//
#include <hip/hip_runtime.h>
#include <math.h>

typedef float v2f __attribute__((ext_vector_type(2)));

constexpr int NW = 14;
constexpr int DIM = 1 << NW;      // 16384
constexpr int BATCH = 256;
constexpr int NT = 512;           // 8 waves; each thread owns 32 amplitudes (16 v2f pairs)

// LDS bank swizzle: XOR bits 9..5 into 4..0 (bijective; measured 0 conflicts in R2).
__device__ __forceinline__ int swz(int i) { return i ^ ((i >> 5) & 31); }

// ---------------------------------------------------------------------------
// Uniform packed gate: JW, JT in {0..3}; packed dim (local bit 4) is a
// spectator, so each scalar line becomes one v_pk op on both halves.
template<int JW, int JT>
__device__ __forceinline__ void gate_u(v2f (&pr)[16], v2f (&pi)[16],
                                       float cy, float sy, float c1, float s1,
                                       float cx, float sx)
{
    constexpr int BW = 1 << JW, BT = 1 << JT;
    #pragma unroll
    for (int m = 0; m < 4; ++m) {
        int l00 = 0, mm = m;
        #pragma unroll
        for (int j = 0; j < 4; ++j)
            if (j != JW && j != JT) { l00 |= (mm & 1) << j; mm >>= 1; }
        const int iA = l00, iB = l00 | BW, iC = l00 | BT, iD = l00 | BW | BT;

        v2f a00r = pr[iA], a00i = pi[iA];
        v2f a10r = pr[iB], a10i = pi[iB];
        v2f a01r = pr[iC], a01i = pi[iC];
        v2f a11r = pr[iD], a11i = pi[iD];

        // RY (real) on wire bit
        v2f v0r = cy*a00r - sy*a10r, v0i = cy*a00i - sy*a10i;
        v2f v1r = sy*a00r + cy*a10r, v1i = sy*a00i + cy*a10i;
        v2f u0r = cy*a01r - sy*a11r, u0i = cy*a01i - sy*a11i;
        v2f u1r = sy*a01r + cy*a11r, u1i = sy*a01i + cy*a11i;

        // RZ phase on wire bit
        v2f b00r = c1*v0r + s1*v0i, b00i = c1*v0i - s1*v0r;
        v2f b10r = c1*v1r - s1*v1i, b10i = c1*v1i + s1*v1r;
        v2f b01r = c1*u0r + s1*u0i, b01i = c1*u0i - s1*u0r;
        v2f b11r = c1*u1r - s1*u1i, b11i = c1*u1i + s1*u1r;

        // CNOT(w->t) then RX(w)
        v2f o00r = cx*b00r + sx*b11i, o00i = cx*b00i - sx*b11r;
        v2f o10r = sx*b00i + cx*b11r, o10i = cx*b11i - sx*b00r;
        v2f o01r = cx*b01r + sx*b10i, o01i = cx*b01i - sx*b10r;
        v2f o11r = sx*b01i + cx*b10r, o11i = cx*b10i - sx*b01r;

        pr[iA] = o00r; pi[iA] = o00i;
        pr[iB] = o10r; pi[iB] = o10i;
        pr[iC] = o01r; pi[iC] = o01i;
        pr[iD] = o11r; pi[iD] = o11i;
    }
}

// Clean packed gate: wire = local bit 0, target = packed dim (local bit 4).
// P0 = row w=0 packs (b00,b01) over t; P1 = row w=1 packs (b10,b11).
// CNOT+RX becomes cx*P0 +/- sx*swap(P1)  (swap -> op_sel / 1 mov).
__device__ __forceinline__ void gate_c(v2f (&pr)[16], v2f (&pi)[16],
                                       float cy, float sy, float c1, float s1,
                                       float cx, float sx)
{
    #pragma unroll
    for (int m = 0; m < 8; ++m) {
        const int iA = m << 1, iB = iA | 1;
        v2f Ar = pr[iA], Ai = pi[iA];   // (a00, a01)
        v2f Br = pr[iB], Bi = pi[iB];   // (a10, a11)

        // RY on wire bit (uniform over packed target dim)
        v2f Vr = cy*Ar - sy*Br, Vi = cy*Ai - sy*Bi;   // w=0 row
        v2f Wr = sy*Ar + cy*Br, Wi = sy*Ai + cy*Bi;   // w=1 row

        // RZ on wire bit
        v2f P0r = c1*Vr + s1*Vi, P0i = c1*Vi - s1*Vr;
        v2f P1r = c1*Wr - s1*Wi, P1i = c1*Wi + s1*Wr;

        v2f sP1r = {P1r.y, P1r.x};
        v2f sP1i = {P1i.y, P1i.x};

        pr[iA] = cx*P0r + sx*sP1i;   // (o00r, o01r)
        pi[iA] = cx*P0i - sx*sP1r;   // (o00i, o01i)
        pr[iB] = sx*P0i + cx*sP1r;   // (o10r, o11r)
        pi[iB] = cx*sP1i - sx*P0r;   // (o10i, o11i)
    }
}

// ---------------------------------------------------------------------------
// Scatter thread id t (9 bits) into the 9 bit-positions NOT in {P0..P4}.
template<int P0, int P1, int P2, int P3, int P4>
__device__ __forceinline__ int base_of(int t)
{
    int base = 0, j = 0;
    #pragma unroll
    for (int p = 0; p < NW; ++p) {
        if (p != P0 && p != P1 && p != P2 && p != P3 && p != P4) {
            base |= ((t >> j) & 1) << p;
            ++j;
        }
    }
    return base;
}

template<int P0, int P1, int P2, int P3, int P4>
__device__ __forceinline__ int off_of(int l)
{
    return ((l & 1) << P0) | (((l >> 1) & 1) << P1) | (((l >> 2) & 1) << P2) |
           (((l >> 3) & 1) << P3) | (((l >> 4) & 1) << P4);
}

template<int P0, int P1, int P2, int P3, int P4>
__device__ __forceinline__ void lds_load_pk(const float* re, const float* im,
                                            v2f (&pr)[16], v2f (&pi)[16], int base)
{
    #pragma unroll
    for (int k = 0; k < 16; ++k) {
        const int s0 = swz(base | off_of<P0, P1, P2, P3, P4>(k));
        const int s1_ = swz(base | off_of<P0, P1, P2, P3, P4>(k | 16));
        pr[k] = v2f{re[s0], re[s1_]};
        pi[k] = v2f{im[s0], im[s1_]};
    }
}

template<int P0, int P1, int P2, int P3, int P4>
__device__ __forceinline__ void lds_store_pk(float* re, float* im,
                                             const v2f (&pr)[16], const v2f (&pi)[16], int base)
{
    #pragma unroll
    for (int k = 0; k < 16; ++k) {
        const int s0 = swz(base | off_of<P0, P1, P2, P3, P4>(k));
        const int s1_ = swz(base | off_of<P0, P1, P2, P3, P4>(k | 16));
        re[s0] = pr[k].x; re[s1_] = pr[k].y;
        im[s0] = pi[k].x; im[s1_] = pi[k].y;
    }
}

__global__ __launch_bounds__(NT, 1) void qsim(const float* __restrict__ state,
                                              const float* __restrict__ params,
                                              const float* __restrict__ head_w,
                                              const float* __restrict__ head_b,
                                              float* __restrict__ out)
{
    __shared__ float re[DIM];           // 64 KiB
    __shared__ float im[DIM];           // 64 KiB
    __shared__ float2 csv[NW * 3 * 2];  // (cos, sin) of half-angles, 84 gates
    __shared__ float partial[NT / 64];

    const int t = threadIdx.x;
    const int b = blockIdx.x;

    v2f pr[16], pi[16];

    // Pass A register layout: P = <10,11,12,13,9>, base = t (bits 0..8).
    // amp index = t | (k bits -> 10..13) | (half -> bit 9). Coalesced loads.
    const float* __restrict__ sp = state + (size_t)b * DIM;
    #pragma unroll
    for (int k = 0; k < 16; ++k) {
        pr[k] = v2f{sp[t | (k << 10)], sp[t | (k << 10) | 512]};
        pi[k] = v2f{0.0f, 0.0f};
    }

    if (t < NW * 3 * 2) {
        float sv, cv;
        sincosf(params[t] * 0.5f, &sv, &cv);
        csv[t] = make_float2(cv, sv);
    }
    __syncthreads();

#define GATEU(JW, JT, G) do {                                           \
        float2 vy = csv[(G) * 3 + 0];                                   \
        float2 vz = csv[(G) * 3 + 1];                                   \
        float2 vx = csv[(G) * 3 + 2];                                   \
        gate_u<JW, JT>(pr, pi, vy.x, vy.y, vz.x, vz.y, vx.x, vx.y);     \
    } while (0)
#define GATEC(G) do {                                                   \
        float2 vy = csv[(G) * 3 + 0];                                   \
        float2 vz = csv[(G) * 3 + 1];                                   \
        float2 vx = csv[(G) * 3 + 2];                                   \
        gate_c(pr, pi, vy.x, vy.y, vz.x, vz.y, vx.x, vx.y);             \
    } while (0)

    // Every pass: 3 uniform gates + 1 clean-target gate (packed bit = P4 =
    // target-only bit of the pass's gate chain).

    // Pass A: L1 wires 0-3, P=<10,11,12,13,9>, gates 0..3
    GATEU(3, 2, 0); GATEU(2, 1, 1); GATEU(1, 0, 2); GATEC(3);
    lds_store_pk<10, 11, 12, 13, 9>(re, im, pr, pi, base_of<10, 11, 12, 13, 9>(t));
    __syncthreads();

    // Pass B: L1 wires 4-7, P=<6,7,8,9,5>, gates 4..7
    {
        const int base = base_of<6, 7, 8, 9, 5>(t);
        lds_load_pk<6, 7, 8, 9, 5>(re, im, pr, pi, base);
        GATEU(3, 2, 4); GATEU(2, 1, 5); GATEU(1, 0, 6); GATEC(7);
        lds_store_pk<6, 7, 8, 9, 5>(re, im, pr, pi, base);
    }
    __syncthreads();

    // Pass C: L1 wires 8-11, P=<2,3,4,5,1>, gates 8..11
    {
        const int base = base_of<2, 3, 4, 5, 1>(t);
        lds_load_pk<2, 3, 4, 5, 1>(re, im, pr, pi, base);
        GATEU(3, 2, 8); GATEU(2, 1, 9); GATEU(1, 0, 10); GATEC(11);
        lds_store_pk<2, 3, 4, 5, 1>(re, im, pr, pi, base);
    }
    __syncthreads();

    // Pass D: L1 wires 12,13 + L2 wires 0,1, P=<12,13,0,1,11>, gates 12..15
    {
        const int base = base_of<12, 13, 0, 1, 11>(t);
        lds_load_pk<12, 13, 0, 1, 11>(re, im, pr, pi, base);
        GATEU(3, 2, 12); GATEU(2, 1, 13); GATEU(1, 0, 14); GATEC(15);
        lds_store_pk<12, 13, 0, 1, 11>(re, im, pr, pi, base);
    }
    __syncthreads();

    // Pass E: L2 wires 2-5, P=<8,9,10,11,7>, gates 16..19
    {
        const int base = base_of<8, 9, 10, 11, 7>(t);
        lds_load_pk<8, 9, 10, 11, 7>(re, im, pr, pi, base);
        GATEU(3, 2, 16); GATEU(2, 1, 17); GATEU(1, 0, 18); GATEC(19);
        lds_store_pk<8, 9, 10, 11, 7>(re, im, pr, pi, base);
    }
    __syncthreads();

    // Pass F: L2 wires 6-9, P=<4,5,6,7,3>, gates 20..23
    {
        const int base = base_of<4, 5, 6, 7, 3>(t);
        lds_load_pk<4, 5, 6, 7, 3>(re, im, pr, pi, base);
        GATEU(3, 2, 20); GATEU(2, 1, 21); GATEU(1, 0, 22); GATEC(23);
        lds_store_pk<4, 5, 6, 7, 3>(re, im, pr, pi, base);
    }
    __syncthreads();

    // Pass G: L2 wires 10-13, P=<0,1,2,3,13>, gates 24..27; epilogue from regs.
    {
        const int base = base_of<0, 1, 2, 3, 13>(t);
        lds_load_pk<0, 1, 2, 3, 13>(re, im, pr, pi, base);
        GATEU(3, 2, 24); GATEU(2, 1, 25); GATEU(1, 0, 26); GATEC(27);
    }

    // Epilogue: out[b] = sum_i |amp_i|^2 * g(i) + head_b.
    // k bits 0..3 -> global bits 0..3 -> wires 13,12,11,10; packed half -> bit 13
    // -> wire 0; thread bits -> global 4..12 -> wires 9..1.
    float hw[NW];
    #pragma unroll
    for (int w = 0; w < NW; ++w) hw[w] = head_w[w];

    float gbase = 0.0f;
    #pragma unroll
    for (int j = 0; j < 9; ++j) {
        float h = hw[9 - j];
        gbase += ((t >> j) & 1) ? -h : h;
    }

    v2f acc2 = {0.0f, 0.0f};
    #pragma unroll
    for (int k = 0; k < 16; ++k) {
        float gk = gbase;
        gk += (k & 1) ? -hw[13] : hw[13];
        gk += (k & 2) ? -hw[12] : hw[12];
        gk += (k & 4) ? -hw[11] : hw[11];
        gk += (k & 8) ? -hw[10] : hw[10];
        v2f g = {gk + hw[0], gk - hw[0]};
        acc2 += (pr[k] * pr[k] + pi[k] * pi[k]) * g;
    }
    float acc = acc2.x + acc2.y;

    #pragma unroll
    for (int off = 32; off > 0; off >>= 1) acc += __shfl_down(acc, off);
    if ((t & 63) == 0) partial[t >> 6] = acc;
    __syncthreads();
    if (t == 0) {
        float tot = 0.0f;
        #pragma unroll
        for (int k = 0; k < NT / 64; ++k) tot += partial[k];
        out[b] = tot + head_b[0];
    }
#undef GATEU
#undef GATEC
}

extern "C" void kernel_launch(void* const* d_in, const int* in_sizes, int n_in,
                              void* d_out, int out_size, void* d_ws, size_t ws_size,
                              hipStream_t stream) {
    const float* state  = (const float*)d_in[0];
    const float* params = (const float*)d_in[1];
    const float* head_w = (const float*)d_in[2];
    const float* head_b = (const float*)d_in[3];
    float* outp = (float*)d_out;
    qsim<<<BATCH, NT, 0, stream>>>(state, params, head_w, head_b, outp);
}